// Round 26
// baseline (85.257 us; speedup 1.0000x reference)
//
#include <hip/hip_runtime.h>
#include <hip/hip_fp16.h>

// Problem constants
#define BB 2
#define CC 64
#define KK 27
#define S_TOT 32768  // 32^3
#define BN_EPS 1e-5f
#define SV_STRIDE 66
#define KL_STRIDE 66

typedef _Float16 h8 __attribute__((ext_vector_type(8)));
typedef _Float16 h4v __attribute__((ext_vector_type(4)));
typedef float f4v __attribute__((ext_vector_type(4)));

// ws layout: xT[2][32768][64] HALVES (8.4 MB).
#define XT_HALVES ((size_t)BB * S_TOT * CC)

// ---------------------------------------------------------------------------
// K1: transpose x[b][c][s] -> xT[b][s][c] in FP16 (R25-proven).
// ---------------------------------------------------------------------------
__global__ __launch_bounds__(256) void xpose_kernel(const float* __restrict__ x,
                                                    __half* __restrict__ xT) {
  __shared__ float t[64 * 65];
  const int tid = threadIdx.x;
  const int blk = blockIdx.x;
  const int b   = blk >> 9;
  const int s0  = (blk & 511) << 6;
  const float* xb = x + ((size_t)b << 21);
  {
    const int cq = tid >> 4;
    const int sq = (tid & 15) << 2;
#pragma unroll
    for (int i = 0; i < 4; ++i) {
      int c = cq + (i << 4);
      float4 v = *(const float4*)(xb + ((size_t)c << 15) + s0 + sq);
      t[c * 65 + sq + 0] = v.x;
      t[c * 65 + sq + 1] = v.y;
      t[c * 65 + sq + 2] = v.z;
      t[c * 65 + sq + 3] = v.w;
    }
  }
  __syncthreads();
  {
    _Float16* xTb = (_Float16*)xT + ((size_t)b << 21);
    const int si = tid >> 2;
    const int cb = (tid & 3) << 4;
#pragma unroll
    for (int j = 0; j < 4; ++j) {
      int c = cb + (j << 2);
      h4v hv;
      hv[0] = (_Float16)t[(c + 0) * 65 + si];
      hv[1] = (_Float16)t[(c + 1) * 65 + si];
      hv[2] = (_Float16)t[(c + 2) * 65 + si];
      hv[3] = (_Float16)t[(c + 3) * 65 + si];
      *(h4v*)(xTb + ((size_t)(s0 + si) << 6) + c) = hv;
    }
  }
}

// ---------------------------------------------------------------------------
// K2: FUSED — R25 champion (fp16 xT gather, 77us fused) + R23's phase-1
// MFMA (individually verified: correct, VALUBusy 22.7->14.9, VGPR 32, no
// spill; was neutral ONLY because the old vmem floor hid it — that floor
// dropped 20us in R25, so the phase-1 VALU cut should now be visible).
//   Phase 0: offs u16 -> LDS
//   Phase 1: GEMM1 via MFMA + BN + ReLU -> sv fp16 (R23 recipe: B = x cols
//            fp16-cast, A = wr rows fp16-cast, 4 row-tiles runtime loop,
//            C-frag o = rt*16 + hi*4 + r)
//   Phase 2: GEMM2 via MFMA -> kl fp16 (aliases sv; B-frags then barrier)
//   Phase 3: gather from FP16 xT — ONE 16B load per k (R25), unroll 3
// LDS: union(sv,kl) 13.9K + offs 3.4K = 17.7KB. Cap (256,4) = 128 VGPR.
// ---------------------------------------------------------------------------
__global__ __launch_bounds__(256, 4) void invol_fused_xt(
    const float* __restrict__ x, const __half* __restrict__ xT,
    const float* __restrict__ wr, const float* __restrict__ wsp,
    const float* __restrict__ gamma, const float* __restrict__ beta,
    const float* __restrict__ mean, const float* __restrict__ var,
    float* __restrict__ out) {
  __shared__ __half svkl[108 * KL_STRIDE];     // 13.9 KB: sv then kl (alias)
  __shared__ unsigned short offs[KK * 64];     // 3.375 KB   -> total 17.7 KB
  __half* sv = svkl;
  __half* kl = svkl;

  const int tid = threadIdx.x;
  const int blk = blockIdx.x;
  const int b   = blk >> 10;
  const int p   = (blk >> 9) & 1;
  const int s0  = (blk & 511) << 6;
  const int si  = tid & 63;
  const int w   = __builtin_amdgcn_readfirstlane(tid >> 6);  // wave 0..3
  const int g   = (p << 2) + w;                               // group 0..7
  const int c0  = g << 3;

  // ---- Phase 0: offset table ----
  // f = k*32768 + s, mixed radix [od:32][oh:32][ow:32][kd:3][kh:3][kw:3];
  // (dd,hh,ww) = (od+kd-1, oh+kh-1, ow+kw-1); 0xFFFF if OOB (zero pad).
  for (int i = tid; i < KK * 64; i += 256) {
    int k  = i >> 6;
    int f  = (k << 15) + s0 + (i & 63);
    int kw = f % 3; int u = f / 3;
    int kh = u % 3; u /= 3;
    int kd = u % 3; u /= 3;
    int ww = (u & 31) + kw - 1; u >>= 5;
    int hh = (u & 31) + kh - 1; u >>= 5;
    int dd = u + kd - 1;
    unsigned short off = 0xFFFFu;
    if (((unsigned)ww < 32u) & ((unsigned)hh < 32u) & ((unsigned)dd < 32u))
      off = (unsigned short)((dd << 10) + (hh << 5) + ww);
    offs[i] = off;
  }

  const int lane = tid & 63;
  const int lo   = lane & 15;       // row (A) / col (B,C) within 16x16 tile
  const int hi   = lane >> 4;       // k-group
  const int kb   = hi << 3;         // k base within 32-chunk
  const int col  = (w << 4) + lo;   // this wave's col-tile = w

  // ---- Phase 1: GEMM1 via MFMA + BN + ReLU -> sv fp16 (R23 recipe) ----
  {
    const float* xcol = x + ((size_t)b << 21) + s0 + col;  // x[c][s0+col]
    h8 xb0, xb1;
#pragma unroll
    for (int e = 0; e < 8; ++e) {
      xb0[e] = (_Float16)xcol[(size_t)(kb + e) << 15];
      xb1[e] = (_Float16)xcol[(size_t)(32 + kb + e) << 15];
    }
#pragma unroll 1
    for (int rt = 0; rt < 4; ++rt) {
      const float* ar = wr + (rt * 16 + lo) * CC;
      float4 va0 = *(const float4*)(ar + kb);
      float4 va1 = *(const float4*)(ar + kb + 4);
      float4 vb0 = *(const float4*)(ar + 32 + kb);
      float4 vb1 = *(const float4*)(ar + 32 + kb + 4);
      h8 a0, a1;
      a0[0] = (_Float16)va0.x; a0[1] = (_Float16)va0.y;
      a0[2] = (_Float16)va0.z; a0[3] = (_Float16)va0.w;
      a0[4] = (_Float16)va1.x; a0[5] = (_Float16)va1.y;
      a0[6] = (_Float16)va1.z; a0[7] = (_Float16)va1.w;
      a1[0] = (_Float16)vb0.x; a1[1] = (_Float16)vb0.y;
      a1[2] = (_Float16)vb0.z; a1[3] = (_Float16)vb0.w;
      a1[4] = (_Float16)vb1.x; a1[5] = (_Float16)vb1.y;
      a1[6] = (_Float16)vb1.z; a1[7] = (_Float16)vb1.w;
      f4v acc = {0.f, 0.f, 0.f, 0.f};
      acc = __builtin_amdgcn_mfma_f32_16x16x32_f16(a0, xb0, acc, 0, 0, 0);
      acc = __builtin_amdgcn_mfma_f32_16x16x32_f16(a1, xb1, acc, 0, 0, 0);
#pragma unroll
      for (int r = 0; r < 4; ++r) {
        int o = rt * 16 + (hi << 2) + r;     // output channel (C-frag row)
        float v = (acc[r] - mean[o]) * rsqrtf(var[o] + BN_EPS) * gamma[o] + beta[o];
        sv[o * SV_STRIDE + col] = __float2half(v > 0.f ? v : 0.f);
      }
    }
  }
  __syncthreads();  // sv + offs ready

  // ---- Phase 2: GEMM2 via MFMA -> kl fp16 (kl aliases sv) ----
  {
    const _Float16* svh = (const _Float16*)sv;
    _Float16* klh = (_Float16*)kl;

    // Phase 2a: B fragments from sv — the LAST reads of sv.
    h8 b0, b1;
#pragma unroll
    for (int e = 0; e < 8; ++e) {
      b0[e] = svh[(kb + e) * SV_STRIDE + col];
      b1[e] = svh[(32 + kb + e) * SV_STRIDE + col];
    }
    __syncthreads();  // all B-frag reads complete before kl overwrites sv

    // Phase 2b: MFMA row-tile loop, writes kl over the union buffer.
    const int rt0 = 6 * p;            // p=0: tiles 0..6 ; p=1: tiles 6..13
    const int rt1 = 7 + 7 * p;
    const int lbase = 108 * p;
#pragma unroll 1
    for (int rt = rt0; rt < rt1; ++rt) {
      int row  = (rt << 4) + lo;
      int rowc = row > 215 ? 215 : row;         // clamp A OOB (masked below)
      const float* ar = wsp + rowc * CC;
      float4 va0 = *(const float4*)(ar + kb);
      float4 va1 = *(const float4*)(ar + kb + 4);
      float4 vb0 = *(const float4*)(ar + 32 + kb);
      float4 vb1 = *(const float4*)(ar + 32 + kb + 4);
      h8 a0, a1;
      a0[0] = (_Float16)va0.x; a0[1] = (_Float16)va0.y;
      a0[2] = (_Float16)va0.z; a0[3] = (_Float16)va0.w;
      a0[4] = (_Float16)va1.x; a0[5] = (_Float16)va1.y;
      a0[6] = (_Float16)va1.z; a0[7] = (_Float16)va1.w;
      a1[0] = (_Float16)vb0.x; a1[1] = (_Float16)vb0.y;
      a1[2] = (_Float16)vb0.z; a1[3] = (_Float16)vb0.w;
      a1[4] = (_Float16)vb1.x; a1[5] = (_Float16)vb1.y;
      a1[6] = (_Float16)vb1.z; a1[7] = (_Float16)vb1.w;
      f4v acc = {0.f, 0.f, 0.f, 0.f};
      acc = __builtin_amdgcn_mfma_f32_16x16x32_f16(a0, b0, acc, 0, 0, 0);
      acc = __builtin_amdgcn_mfma_f32_16x16x32_f16(a1, b1, acc, 0, 0, 0);
#pragma unroll
      for (int r = 0; r < 4; ++r) {
        int kr = (rt << 4) + (hi << 2) + r;     // global kernel-row
        int lr = kr - lbase;                    // local row 27w'+k
        if ((unsigned)lr < 108u)
          klh[lr * KL_STRIDE + col] = (_Float16)acc[r];
      }
    }
  }
  __syncthreads();  // kl produced cross-wave

  // ---- Phase 3: gather-reduce from FP16 xT — ONE 16B load per k ----
  {
    const _Float16* xTb = (const _Float16*)xT + ((size_t)b << 21) + c0;
    const __half* klr = kl + (w * KK) * KL_STRIDE + si;
    float oacc[8];
#pragma unroll
    for (int i = 0; i < 8; ++i) oacc[i] = 0.f;

#pragma unroll 3
    for (int k = 0; k < KK; ++k) {
      unsigned off = offs[(k << 6) + si];
      float kvr = __half2float(klr[k * KL_STRIDE]);
      float kv  = (off != 0xFFFFu) ? kvr : 0.f;
      unsigned o2 = (off != 0xFFFFu) ? off : 0u;
      h8 hv = *(const h8*)(xTb + ((size_t)o2 << 6));
      oacc[0] = fmaf(kv, (float)hv[0], oacc[0]);
      oacc[1] = fmaf(kv, (float)hv[1], oacc[1]);
      oacc[2] = fmaf(kv, (float)hv[2], oacc[2]);
      oacc[3] = fmaf(kv, (float)hv[3], oacc[3]);
      oacc[4] = fmaf(kv, (float)hv[4], oacc[4]);
      oacc[5] = fmaf(kv, (float)hv[5], oacc[5]);
      oacc[6] = fmaf(kv, (float)hv[6], oacc[6]);
      oacc[7] = fmaf(kv, (float)hv[7], oacc[7]);
    }

    float* ob = out + (((size_t)b * CC + c0) << 15) + s0 + si;
#pragma unroll
    for (int i = 0; i < 8; ++i) ob[(size_t)i << 15] = oacc[i];
  }
}

// ---------------------------------------------------------------------------
// Fallback (ws too small): exact R4 fused kernel — known-good 144 us.
// ---------------------------------------------------------------------------
__global__ __launch_bounds__(256, 8) void invol_fused(
    const float* __restrict__ x, const float* __restrict__ wr,
    const float* __restrict__ wsp, const float* __restrict__ gamma,
    const float* __restrict__ beta, const float* __restrict__ mean,
    const float* __restrict__ var, float* __restrict__ out) {
  __shared__ float sv[CC * 64];
  __shared__ int offs[KK * 64];

  const int tid = threadIdx.x;
  const int blk = blockIdx.x;
  const int b   = blk >> 10;
  const int p   = (blk >> 9) & 1;
  const int s0  = (blk & 511) << 6;
  const int si  = tid & 63;
  const int w   = __builtin_amdgcn_readfirstlane(tid >> 6);
  const int g   = (p << 2) + w;

  const float* xb  = x + ((size_t)b << 21);
  const float* xs0 = xb + s0 + si;

  for (int i = tid; i < KK * 64; i += 256) {
    int k  = i >> 6;
    int f  = (k << 15) + s0 + (i & 63);
    int kw = f % 3; int u = f / 3;
    int kh = u % 3; u /= 3;
    int kd = u % 3; u /= 3;
    int ww = (u & 31) + kw - 1; u >>= 5;
    int hh = (u & 31) + kh - 1; u >>= 5;
    int dd = u + kd - 1;
    int off = -1;
    if (((unsigned)ww < 32u) & ((unsigned)hh < 32u) & ((unsigned)dd < 32u))
      off = (dd << 10) + (hh << 5) + ww;
    offs[i] = off;
  }

  {
    float acc[16];
#pragma unroll
    for (int j = 0; j < 16; ++j) acc[j] = 0.f;
#pragma unroll
    for (int half = 0; half < 2; ++half) {
      float xv[32];
#pragma unroll
      for (int c = 0; c < 32; ++c)
        xv[c] = xs0[(size_t)(half * 32 + c) << 15];
      const float* wrw = wr + (w * 16) * CC + half * 32;
#pragma unroll
      for (int j = 0; j < 16; ++j) {
        const float* r0 = wrw + j * CC;
        float a0 = 0.f, a1 = 0.f;
#pragma unroll
        for (int c = 0; c < 32; c += 2) {
          a0 = fmaf(r0[c],     xv[c],     a0);
          a1 = fmaf(r0[c + 1], xv[c + 1], a1);
        }
        acc[j] += a0 + a1;
      }
    }
#pragma unroll
    for (int j = 0; j < 16; ++j) {
      int o = w * 16 + j;
      float v = (acc[j] - mean[o]) * rsqrtf(var[o] + BN_EPS) * gamma[o] + beta[o];
      sv[o * 64 + si] = v > 0.f ? v : 0.f;
    }
  }
  __syncthreads();

  float kreg[27];
#pragma unroll
  for (int j = 0; j < KK; ++j) kreg[j] = 0.f;
#pragma unroll
  for (int e = 0; e < 8; ++e) {
    float xv[8];
#pragma unroll
    for (int c = 0; c < 8; ++c) xv[c] = sv[(e * 8 + c) * 64 + si];
    const float* wsw = wsp + (g * KK) * CC + e * 8;
#pragma unroll
    for (int j = 0; j < KK; ++j) {
      const float* r = wsw + j * CC;
      float a0 = 0.f, a1 = 0.f;
#pragma unroll
      for (int c = 0; c < 8; c += 2) {
        a0 = fmaf(r[c],     xv[c],     a0);
        a1 = fmaf(r[c + 1], xv[c + 1], a1);
      }
      kreg[j] += a0 + a1;
    }
  }

  {
    const int c0 = g << 3;
    const float* xc0 = xb + ((size_t)c0 << 15);
    float oacc[8];
#pragma unroll
    for (int i = 0; i < 8; ++i) oacc[i] = 0.f;
#pragma unroll
    for (int k = 0; k < KK; ++k) {
      int off = offs[(k << 6) + si];
      float kv = kreg[k];
      if (off >= 0) {
#pragma unroll
        for (int c8 = 0; c8 < 8; ++c8)
          oacc[c8] = fmaf(kv, xc0[off + (c8 << 15)], oacc[c8]);
      }
    }
    float* ob = out + (((size_t)b * CC + c0) << 15) + s0 + si;
#pragma unroll
    for (int i = 0; i < 8; ++i) ob[(size_t)i << 15] = oacc[i];
  }
}

extern "C" void kernel_launch(void* const* d_in, const int* in_sizes, int n_in,
                              void* d_out, int out_size, void* d_ws, size_t ws_size,
                              hipStream_t stream) {
  const float* x     = (const float*)d_in[0];
  const float* wr    = (const float*)d_in[1];
  const float* wsp   = (const float*)d_in[2];
  const float* gamma = (const float*)d_in[3];
  const float* beta  = (const float*)d_in[4];
  const float* mean  = (const float*)d_in[5];
  const float* var   = (const float*)d_in[6];
  float* out = (float*)d_out;

  const size_t need = XT_HALVES * sizeof(__half);  // 8.4 MB
  if (ws_size >= need) {
    __half* xT = (__half*)d_ws;
    xpose_kernel<<<BB * (S_TOT / 64), 256, 0, stream>>>(x, xT);
    invol_fused_xt<<<BB * 2 * (S_TOT / 64), 256, 0, stream>>>(
        x, xT, wr, wsp, gamma, beta, mean, var, out);
  } else {
    invol_fused<<<BB * 2 * (S_TOT / 64), 256, 0, stream>>>(
        x, wr, wsp, gamma, beta, mean, var, out);
  }
}

// Round 27
// 72.506 us; speedup vs baseline: 1.1759x; 1.1759x over previous
//
#include <hip/hip_runtime.h>
#include <hip/hip_fp16.h>

// Problem constants
#define BB 2
#define CC 64
#define KK 27
#define S_TOT 32768  // 32^3
#define BN_EPS 1e-5f
#define SV_STRIDE 66
#define KL_STRIDE 66

typedef _Float16 h8 __attribute__((ext_vector_type(8)));
typedef _Float16 h4v __attribute__((ext_vector_type(4)));
typedef float f4v __attribute__((ext_vector_type(4)));

// ws layout: xTg[2][8][32768][8] halves (8.4 MB) — GROUP-MAJOR fp16.
// One 128B cache line = 8 consecutive spatial positions of ONE group, so the
// gather's clustered offsets touch ~4-8 lines/wave-load instead of 20-30
// (previous layout: one line = one position's 64 channels, 16B used).
#define XT_HALVES ((size_t)BB * S_TOT * CC)

// ---------------------------------------------------------------------------
// K1: transpose x[b][c][s] -> xTg[b][g][s][c%8] in FP16 (group-major).
// ---------------------------------------------------------------------------
__global__ __launch_bounds__(256) void xpose_kernel(const float* __restrict__ x,
                                                    __half* __restrict__ xT) {
  __shared__ float t[64 * 65];
  const int tid = threadIdx.x;
  const int blk = blockIdx.x;
  const int b   = blk >> 9;
  const int s0  = (blk & 511) << 6;
  const float* xb = x + ((size_t)b << 21);
  {
    const int cq = tid >> 4;
    const int sq = (tid & 15) << 2;
#pragma unroll
    for (int i = 0; i < 4; ++i) {
      int c = cq + (i << 4);
      float4 v = *(const float4*)(xb + ((size_t)c << 15) + s0 + sq);
      t[c * 65 + sq + 0] = v.x;
      t[c * 65 + sq + 1] = v.y;
      t[c * 65 + sq + 2] = v.z;
      t[c * 65 + sq + 3] = v.w;
    }
  }
  __syncthreads();
  {
    const int si = tid >> 2;
    const int cb = (tid & 3) << 4;
#pragma unroll
    for (int j = 0; j < 4; ++j) {
      int c  = cb + (j << 2);          // multiple of 4 -> one group, cc in {0,4}
      int gg = c >> 3;
      int cc = c & 7;
      _Float16* dst = (_Float16*)xT +
          ((((size_t)(b * 8 + gg) << 15) + (s0 + si)) << 3) + cc;
      h4v hv;
      hv[0] = (_Float16)t[(c + 0) * 65 + si];
      hv[1] = (_Float16)t[(c + 1) * 65 + si];
      hv[2] = (_Float16)t[(c + 2) * 65 + si];
      hv[3] = (_Float16)t[(c + 3) * 65 + si];
      *(h4v*)dst = hv;
    }
  }
}

// ---------------------------------------------------------------------------
// K2: FUSED — R25 champion (scalar phase 1 from x, MFMA phase 2, fp16 xT
// gather; 77us fused / 84.2 total — best) with ONE change: the gather reads
// the GROUP-MAJOR xTg layout (line = 8 positions of one group).
// LDS: union(sv,kl) 13.9K + offs 3.4K = 17.7KB. Cap (256,4) = 128 VGPR.
// ---------------------------------------------------------------------------
__global__ __launch_bounds__(256, 4) void invol_fused_xt(
    const float* __restrict__ x, const __half* __restrict__ xT,
    const float* __restrict__ wr, const float* __restrict__ wsp,
    const float* __restrict__ gamma, const float* __restrict__ beta,
    const float* __restrict__ mean, const float* __restrict__ var,
    float* __restrict__ out) {
  __shared__ __half svkl[108 * KL_STRIDE];     // 13.9 KB: sv then kl (alias)
  __shared__ unsigned short offs[KK * 64];     // 3.375 KB   -> total 17.7 KB
  __half* sv = svkl;
  __half* kl = svkl;

  const int tid = threadIdx.x;
  const int blk = blockIdx.x;
  const int b   = blk >> 10;
  const int p   = (blk >> 9) & 1;
  const int s0  = (blk & 511) << 6;
  const int si  = tid & 63;
  const int w   = __builtin_amdgcn_readfirstlane(tid >> 6);  // wave 0..3
  const int g   = (p << 2) + w;                               // group 0..7
  const int c0  = g << 3;

  // ---- Phase 0: offset table ----
  // f = k*32768 + s, mixed radix [od:32][oh:32][ow:32][kd:3][kh:3][kw:3];
  // (dd,hh,ww) = (od+kd-1, oh+kh-1, ow+kw-1); 0xFFFF if OOB (zero pad).
  for (int i = tid; i < KK * 64; i += 256) {
    int k  = i >> 6;
    int f  = (k << 15) + s0 + (i & 63);
    int kw = f % 3; int u = f / 3;
    int kh = u % 3; u /= 3;
    int kd = u % 3; u /= 3;
    int ww = (u & 31) + kw - 1; u >>= 5;
    int hh = (u & 31) + kh - 1; u >>= 5;
    int dd = u + kd - 1;
    unsigned short off = 0xFFFFu;
    if (((unsigned)ww < 32u) & ((unsigned)hh < 32u) & ((unsigned)dd < 32u))
      off = (unsigned short)((dd << 10) + (hh << 5) + ww);
    offs[i] = off;
  }

  // ---- Phase 1: GEMM1 + BN + ReLU -> sv fp16 (coalesced x reads, R4) ----
  {
    const float* xs0 = x + ((size_t)b << 21) + s0 + si;  // 4B lane-stride
    float acc[16];
#pragma unroll
    for (int j = 0; j < 16; ++j) acc[j] = 0.f;
#pragma unroll
    for (int half = 0; half < 2; ++half) {
      float xv[32];
#pragma unroll
      for (int c = 0; c < 32; ++c)
        xv[c] = xs0[(size_t)(half * 32 + c) << 15];
      const float* wrw = wr + (w * 16) * CC + half * 32;
#pragma unroll
      for (int j = 0; j < 16; ++j) {
        const float* r0 = wrw + j * CC;
        float a0 = 0.f, a1 = 0.f;
#pragma unroll
        for (int c = 0; c < 32; c += 2) {
          a0 = fmaf(r0[c],     xv[c],     a0);
          a1 = fmaf(r0[c + 1], xv[c + 1], a1);
        }
        acc[j] += a0 + a1;
      }
    }
#pragma unroll
    for (int j = 0; j < 16; ++j) {
      int o = w * 16 + j;
      float v = (acc[j] - mean[o]) * rsqrtf(var[o] + BN_EPS) * gamma[o] + beta[o];
      sv[o * SV_STRIDE + si] = __float2half(v > 0.f ? v : 0.f);
    }
  }
  __syncthreads();  // sv + offs ready

  // ---- Phase 2: GEMM2 via MFMA -> kl fp16 (kl aliases sv) ----
  {
    const int lane = tid & 63;
    const int lo   = lane & 15;       // row (A) / col (B,C) within tile
    const int hi   = lane >> 4;       // k-group
    const int kb   = hi << 3;         // k base within 32-chunk
    const int col  = (w << 4) + lo;   // this wave's col-tile = w
    const _Float16* svh = (const _Float16*)sv;
    _Float16* klh = (_Float16*)kl;

    // Phase 2a: B fragments from sv — the LAST reads of sv.
    h8 b0, b1;
#pragma unroll
    for (int e = 0; e < 8; ++e) {
      b0[e] = svh[(kb + e) * SV_STRIDE + col];
      b1[e] = svh[(32 + kb + e) * SV_STRIDE + col];
    }
    __syncthreads();  // all B-frag reads complete before kl overwrites sv

    // Phase 2b: MFMA row-tile loop, writes kl over the union buffer.
    const int rt0 = 6 * p;            // p=0: tiles 0..6 ; p=1: tiles 6..13
    const int rt1 = 7 + 7 * p;
    const int lbase = 108 * p;
#pragma unroll 1
    for (int rt = rt0; rt < rt1; ++rt) {
      int row  = (rt << 4) + lo;
      int rowc = row > 215 ? 215 : row;         // clamp A OOB (masked below)
      const float* ar = wsp + rowc * CC;
      float4 va0 = *(const float4*)(ar + kb);
      float4 va1 = *(const float4*)(ar + kb + 4);
      float4 vb0 = *(const float4*)(ar + 32 + kb);
      float4 vb1 = *(const float4*)(ar + 32 + kb + 4);
      h8 a0, a1;
      a0[0] = (_Float16)va0.x; a0[1] = (_Float16)va0.y;
      a0[2] = (_Float16)va0.z; a0[3] = (_Float16)va0.w;
      a0[4] = (_Float16)va1.x; a0[5] = (_Float16)va1.y;
      a0[6] = (_Float16)va1.z; a0[7] = (_Float16)va1.w;
      a1[0] = (_Float16)vb0.x; a1[1] = (_Float16)vb0.y;
      a1[2] = (_Float16)vb0.z; a1[3] = (_Float16)vb0.w;
      a1[4] = (_Float16)vb1.x; a1[5] = (_Float16)vb1.y;
      a1[6] = (_Float16)vb1.z; a1[7] = (_Float16)vb1.w;
      f4v acc = {0.f, 0.f, 0.f, 0.f};
      acc = __builtin_amdgcn_mfma_f32_16x16x32_f16(a0, b0, acc, 0, 0, 0);
      acc = __builtin_amdgcn_mfma_f32_16x16x32_f16(a1, b1, acc, 0, 0, 0);
#pragma unroll
      for (int r = 0; r < 4; ++r) {
        int kr = (rt << 4) + (hi << 2) + r;     // global kernel-row
        int lr = kr - lbase;                    // local row 27w'+k
        if ((unsigned)lr < 108u)
          klh[lr * KL_STRIDE + col] = (_Float16)acc[r];
      }
    }
  }
  __syncthreads();  // kl produced cross-wave

  // ---- Phase 3: gather-reduce from GROUP-MAJOR fp16 xTg ----
  {
    const _Float16* xTg = (const _Float16*)xT + ((size_t)(b * 8 + g) << 18);
    const __half* klr = kl + (w * KK) * KL_STRIDE + si;
    float oacc[8];
#pragma unroll
    for (int i = 0; i < 8; ++i) oacc[i] = 0.f;

#pragma unroll 3
    for (int k = 0; k < KK; ++k) {
      unsigned off = offs[(k << 6) + si];
      float kvr = __half2float(klr[k * KL_STRIDE]);
      float kv  = (off != 0xFFFFu) ? kvr : 0.f;
      unsigned o2 = (off != 0xFFFFu) ? off : 0u;
      h8 hv = *(const h8*)(xTg + ((size_t)o2 << 3));
      oacc[0] = fmaf(kv, (float)hv[0], oacc[0]);
      oacc[1] = fmaf(kv, (float)hv[1], oacc[1]);
      oacc[2] = fmaf(kv, (float)hv[2], oacc[2]);
      oacc[3] = fmaf(kv, (float)hv[3], oacc[3]);
      oacc[4] = fmaf(kv, (float)hv[4], oacc[4]);
      oacc[5] = fmaf(kv, (float)hv[5], oacc[5]);
      oacc[6] = fmaf(kv, (float)hv[6], oacc[6]);
      oacc[7] = fmaf(kv, (float)hv[7], oacc[7]);
    }

    float* ob = out + (((size_t)b * CC + c0) << 15) + s0 + si;
#pragma unroll
    for (int i = 0; i < 8; ++i) ob[(size_t)i << 15] = oacc[i];
  }
}

// ---------------------------------------------------------------------------
// Fallback (ws too small): exact R4 fused kernel — known-good 144 us.
// ---------------------------------------------------------------------------
__global__ __launch_bounds__(256, 8) void invol_fused(
    const float* __restrict__ x, const float* __restrict__ wr,
    const float* __restrict__ wsp, const float* __restrict__ gamma,
    const float* __restrict__ beta, const float* __restrict__ mean,
    const float* __restrict__ var, float* __restrict__ out) {
  __shared__ float sv[CC * 64];
  __shared__ int offs[KK * 64];

  const int tid = threadIdx.x;
  const int blk = blockIdx.x;
  const int b   = blk >> 10;
  const int p   = (blk >> 9) & 1;
  const int s0  = (blk & 511) << 6;
  const int si  = tid & 63;
  const int w   = __builtin_amdgcn_readfirstlane(tid >> 6);
  const int g   = (p << 2) + w;

  const float* xb  = x + ((size_t)b << 21);
  const float* xs0 = xb + s0 + si;

  for (int i = tid; i < KK * 64; i += 256) {
    int k  = i >> 6;
    int f  = (k << 15) + s0 + (i & 63);
    int kw = f % 3; int u = f / 3;
    int kh = u % 3; u /= 3;
    int kd = u % 3; u /= 3;
    int ww = (u & 31) + kw - 1; u >>= 5;
    int hh = (u & 31) + kh - 1; u >>= 5;
    int dd = u + kd - 1;
    int off = -1;
    if (((unsigned)ww < 32u) & ((unsigned)hh < 32u) & ((unsigned)dd < 32u))
      off = (dd << 10) + (hh << 5) + ww;
    offs[i] = off;
  }

  {
    float acc[16];
#pragma unroll
    for (int j = 0; j < 16; ++j) acc[j] = 0.f;
#pragma unroll
    for (int half = 0; half < 2; ++half) {
      float xv[32];
#pragma unroll
      for (int c = 0; c < 32; ++c)
        xv[c] = xs0[(size_t)(half * 32 + c) << 15];
      const float* wrw = wr + (w * 16) * CC + half * 32;
#pragma unroll
      for (int j = 0; j < 16; ++j) {
        const float* r0 = wrw + j * CC;
        float a0 = 0.f, a1 = 0.f;
#pragma unroll
        for (int c = 0; c < 32; c += 2) {
          a0 = fmaf(r0[c],     xv[c],     a0);
          a1 = fmaf(r0[c + 1], xv[c + 1], a1);
        }
        acc[j] += a0 + a1;
      }
    }
#pragma unroll
    for (int j = 0; j < 16; ++j) {
      int o = w * 16 + j;
      float v = (acc[j] - mean[o]) * rsqrtf(var[o] + BN_EPS) * gamma[o] + beta[o];
      sv[o * 64 + si] = v > 0.f ? v : 0.f;
    }
  }
  __syncthreads();

  float kreg[27];
#pragma unroll
  for (int j = 0; j < KK; ++j) kreg[j] = 0.f;
#pragma unroll
  for (int e = 0; e < 8; ++e) {
    float xv[8];
#pragma unroll
    for (int c = 0; c < 8; ++c) xv[c] = sv[(e * 8 + c) * 64 + si];
    const float* wsw = wsp + (g * KK) * CC + e * 8;
#pragma unroll
    for (int j = 0; j < KK; ++j) {
      const float* r = wsw + j * CC;
      float a0 = 0.f, a1 = 0.f;
#pragma unroll
      for (int c = 0; c < 8; c += 2) {
        a0 = fmaf(r[c],     xv[c],     a0);
        a1 = fmaf(r[c + 1], xv[c + 1], a1);
      }
      kreg[j] += a0 + a1;
    }
  }

  {
    const int c0 = g << 3;
    const float* xc0 = xb + ((size_t)c0 << 15);
    float oacc[8];
#pragma unroll
    for (int i = 0; i < 8; ++i) oacc[i] = 0.f;
#pragma unroll
    for (int k = 0; k < KK; ++k) {
      int off = offs[(k << 6) + si];
      float kv = kreg[k];
      if (off >= 0) {
#pragma unroll
        for (int c8 = 0; c8 < 8; ++c8)
          oacc[c8] = fmaf(kv, xc0[off + (c8 << 15)], oacc[c8]);
      }
    }
    float* ob = out + (((size_t)b * CC + c0) << 15) + s0 + si;
#pragma unroll
    for (int i = 0; i < 8; ++i) ob[(size_t)i << 15] = oacc[i];
  }
}

extern "C" void kernel_launch(void* const* d_in, const int* in_sizes, int n_in,
                              void* d_out, int out_size, void* d_ws, size_t ws_size,
                              hipStream_t stream) {
  const float* x     = (const float*)d_in[0];
  const float* wr    = (const float*)d_in[1];
  const float* wsp   = (const float*)d_in[2];
  const float* gamma = (const float*)d_in[3];
  const float* beta  = (const float*)d_in[4];
  const float* mean  = (const float*)d_in[5];
  const float* var   = (const float*)d_in[6];
  float* out = (float*)d_out;

  const size_t need = XT_HALVES * sizeof(__half);  // 8.4 MB
  if (ws_size >= need) {
    __half* xT = (__half*)d_ws;
    xpose_kernel<<<BB * (S_TOT / 64), 256, 0, stream>>>(x, xT);
    invol_fused_xt<<<BB * 2 * (S_TOT / 64), 256, 0, stream>>>(
        x, xT, wr, wsp, gamma, beta, mean, var, out);
  } else {
    invol_fused<<<BB * 2 * (S_TOT / 64), 256, 0, stream>>>(
        x, wr, wsp, gamma, beta, mean, var, out);
  }
}

// Round 28
// 71.982 us; speedup vs baseline: 1.1844x; 1.0073x over previous
//
#include <hip/hip_runtime.h>
#include <hip/hip_fp16.h>

// Problem constants
#define BB 2
#define CC 64
#define KK 27
#define S_TOT 32768  // 32^3
#define BN_EPS 1e-5f
#define SV_STRIDE 66
#define KL_STRIDE 66

typedef _Float16 h8 __attribute__((ext_vector_type(8)));
typedef _Float16 h4v __attribute__((ext_vector_type(4)));
typedef float f4v __attribute__((ext_vector_type(4)));

// ws layout: xTg[2][8][32768][8] halves (8.4 MB) — GROUP-MAJOR fp16 (R27).
#define XT_HALVES ((size_t)BB * S_TOT * CC)

// ---------------------------------------------------------------------------
// K1: transpose x[b][c][s] -> xTg[b][g][s][c%8] in FP16 (group-major, R27).
// ---------------------------------------------------------------------------
__global__ __launch_bounds__(256) void xpose_kernel(const float* __restrict__ x,
                                                    __half* __restrict__ xT) {
  __shared__ float t[64 * 65];
  const int tid = threadIdx.x;
  const int blk = blockIdx.x;
  const int b   = blk >> 9;
  const int s0  = (blk & 511) << 6;
  const float* xb = x + ((size_t)b << 21);
  {
    const int cq = tid >> 4;
    const int sq = (tid & 15) << 2;
#pragma unroll
    for (int i = 0; i < 4; ++i) {
      int c = cq + (i << 4);
      float4 v = *(const float4*)(xb + ((size_t)c << 15) + s0 + sq);
      t[c * 65 + sq + 0] = v.x;
      t[c * 65 + sq + 1] = v.y;
      t[c * 65 + sq + 2] = v.z;
      t[c * 65 + sq + 3] = v.w;
    }
  }
  __syncthreads();
  {
    const int si = tid >> 2;
    const int cb = (tid & 3) << 4;
#pragma unroll
    for (int j = 0; j < 4; ++j) {
      int c  = cb + (j << 2);          // multiple of 4 -> one group, cc in {0,4}
      int gg = c >> 3;
      int cc = c & 7;
      _Float16* dst = (_Float16*)xT +
          ((((size_t)(b * 8 + gg) << 15) + (s0 + si)) << 3) + cc;
      h4v hv;
      hv[0] = (_Float16)t[(c + 0) * 65 + si];
      hv[1] = (_Float16)t[(c + 1) * 65 + si];
      hv[2] = (_Float16)t[(c + 2) * 65 + si];
      hv[3] = (_Float16)t[(c + 3) * 65 + si];
      *(h4v*)dst = hv;
    }
  }
}

// ---------------------------------------------------------------------------
// K2: FUSED — R27 champion (group-major fp16 xTg gather, 66.3us fused /
// 72.5 total) with ONE change: phase 1 -> MFMA (R23/R26 recipe, twice
// verified correct; cuts VALUBusy ~11pts, VGPR 32, no spill). R26 was
// neutral because the 77us gather floor hid it; floor is now 66us with
// VALU at 37% — the cut should surface.
//   Phase 0: offs u16 -> LDS
//   Phase 1: GEMM1 via MFMA + BN + ReLU -> sv fp16
//   Phase 2: GEMM2 via MFMA -> kl fp16 (aliases sv)
//   Phase 3: gather from GROUP-MAJOR fp16 xTg (R27), unroll 3
// LDS: union(sv,kl) 13.9K + offs 3.4K = 17.7KB. Cap (256,4) = 128 VGPR.
// ---------------------------------------------------------------------------
__global__ __launch_bounds__(256, 4) void invol_fused_xt(
    const float* __restrict__ x, const __half* __restrict__ xT,
    const float* __restrict__ wr, const float* __restrict__ wsp,
    const float* __restrict__ gamma, const float* __restrict__ beta,
    const float* __restrict__ mean, const float* __restrict__ var,
    float* __restrict__ out) {
  __shared__ __half svkl[108 * KL_STRIDE];     // 13.9 KB: sv then kl (alias)
  __shared__ unsigned short offs[KK * 64];     // 3.375 KB   -> total 17.7 KB
  __half* sv = svkl;
  __half* kl = svkl;

  const int tid = threadIdx.x;
  const int blk = blockIdx.x;
  const int b   = blk >> 10;
  const int p   = (blk >> 9) & 1;
  const int s0  = (blk & 511) << 6;
  const int si  = tid & 63;
  const int w   = __builtin_amdgcn_readfirstlane(tid >> 6);  // wave 0..3
  const int g   = (p << 2) + w;                               // group 0..7
  const int c0  = g << 3;

  // ---- Phase 0: offset table ----
  // f = k*32768 + s, mixed radix [od:32][oh:32][ow:32][kd:3][kh:3][kw:3];
  // (dd,hh,ww) = (od+kd-1, oh+kh-1, ow+kw-1); 0xFFFF if OOB (zero pad).
  for (int i = tid; i < KK * 64; i += 256) {
    int k  = i >> 6;
    int f  = (k << 15) + s0 + (i & 63);
    int kw = f % 3; int u = f / 3;
    int kh = u % 3; u /= 3;
    int kd = u % 3; u /= 3;
    int ww = (u & 31) + kw - 1; u >>= 5;
    int hh = (u & 31) + kh - 1; u >>= 5;
    int dd = u + kd - 1;
    unsigned short off = 0xFFFFu;
    if (((unsigned)ww < 32u) & ((unsigned)hh < 32u) & ((unsigned)dd < 32u))
      off = (unsigned short)((dd << 10) + (hh << 5) + ww);
    offs[i] = off;
  }

  const int lane = tid & 63;
  const int lo   = lane & 15;       // row (A) / col (B,C) within 16x16 tile
  const int hi   = lane >> 4;       // k-group
  const int kb   = hi << 3;         // k base within 32-chunk
  const int col  = (w << 4) + lo;   // this wave's col-tile = w

  // ---- Phase 1: GEMM1 via MFMA + BN + ReLU -> sv fp16 (R23 recipe) ----
  {
    const float* xcol = x + ((size_t)b << 21) + s0 + col;  // x[c][s0+col]
    h8 xb0, xb1;
#pragma unroll
    for (int e = 0; e < 8; ++e) {
      xb0[e] = (_Float16)xcol[(size_t)(kb + e) << 15];
      xb1[e] = (_Float16)xcol[(size_t)(32 + kb + e) << 15];
    }
#pragma unroll 1
    for (int rt = 0; rt < 4; ++rt) {
      const float* ar = wr + (rt * 16 + lo) * CC;
      float4 va0 = *(const float4*)(ar + kb);
      float4 va1 = *(const float4*)(ar + kb + 4);
      float4 vb0 = *(const float4*)(ar + 32 + kb);
      float4 vb1 = *(const float4*)(ar + 32 + kb + 4);
      h8 a0, a1;
      a0[0] = (_Float16)va0.x; a0[1] = (_Float16)va0.y;
      a0[2] = (_Float16)va0.z; a0[3] = (_Float16)va0.w;
      a0[4] = (_Float16)va1.x; a0[5] = (_Float16)va1.y;
      a0[6] = (_Float16)va1.z; a0[7] = (_Float16)va1.w;
      a1[0] = (_Float16)vb0.x; a1[1] = (_Float16)vb0.y;
      a1[2] = (_Float16)vb0.z; a1[3] = (_Float16)vb0.w;
      a1[4] = (_Float16)vb1.x; a1[5] = (_Float16)vb1.y;
      a1[6] = (_Float16)vb1.z; a1[7] = (_Float16)vb1.w;
      f4v acc = {0.f, 0.f, 0.f, 0.f};
      acc = __builtin_amdgcn_mfma_f32_16x16x32_f16(a0, xb0, acc, 0, 0, 0);
      acc = __builtin_amdgcn_mfma_f32_16x16x32_f16(a1, xb1, acc, 0, 0, 0);
#pragma unroll
      for (int r = 0; r < 4; ++r) {
        int o = rt * 16 + (hi << 2) + r;     // output channel (C-frag row)
        float v = (acc[r] - mean[o]) * rsqrtf(var[o] + BN_EPS) * gamma[o] + beta[o];
        sv[o * SV_STRIDE + col] = __float2half(v > 0.f ? v : 0.f);
      }
    }
  }
  __syncthreads();  // sv + offs ready

  // ---- Phase 2: GEMM2 via MFMA -> kl fp16 (kl aliases sv) ----
  {
    const _Float16* svh = (const _Float16*)sv;
    _Float16* klh = (_Float16*)kl;

    // Phase 2a: B fragments from sv — the LAST reads of sv.
    h8 b0, b1;
#pragma unroll
    for (int e = 0; e < 8; ++e) {
      b0[e] = svh[(kb + e) * SV_STRIDE + col];
      b1[e] = svh[(32 + kb + e) * SV_STRIDE + col];
    }
    __syncthreads();  // all B-frag reads complete before kl overwrites sv

    // Phase 2b: MFMA row-tile loop, writes kl over the union buffer.
    const int rt0 = 6 * p;            // p=0: tiles 0..6 ; p=1: tiles 6..13
    const int rt1 = 7 + 7 * p;
    const int lbase = 108 * p;
#pragma unroll 1
    for (int rt = rt0; rt < rt1; ++rt) {
      int row  = (rt << 4) + lo;
      int rowc = row > 215 ? 215 : row;         // clamp A OOB (masked below)
      const float* ar = wsp + rowc * CC;
      float4 va0 = *(const float4*)(ar + kb);
      float4 va1 = *(const float4*)(ar + kb + 4);
      float4 vb0 = *(const float4*)(ar + 32 + kb);
      float4 vb1 = *(const float4*)(ar + 32 + kb + 4);
      h8 a0, a1;
      a0[0] = (_Float16)va0.x; a0[1] = (_Float16)va0.y;
      a0[2] = (_Float16)va0.z; a0[3] = (_Float16)va0.w;
      a0[4] = (_Float16)va1.x; a0[5] = (_Float16)va1.y;
      a0[6] = (_Float16)va1.z; a0[7] = (_Float16)va1.w;
      a1[0] = (_Float16)vb0.x; a1[1] = (_Float16)vb0.y;
      a1[2] = (_Float16)vb0.z; a1[3] = (_Float16)vb0.w;
      a1[4] = (_Float16)vb1.x; a1[5] = (_Float16)vb1.y;
      a1[6] = (_Float16)vb1.z; a1[7] = (_Float16)vb1.w;
      f4v acc = {0.f, 0.f, 0.f, 0.f};
      acc = __builtin_amdgcn_mfma_f32_16x16x32_f16(a0, b0, acc, 0, 0, 0);
      acc = __builtin_amdgcn_mfma_f32_16x16x32_f16(a1, b1, acc, 0, 0, 0);
#pragma unroll
      for (int r = 0; r < 4; ++r) {
        int kr = (rt << 4) + (hi << 2) + r;     // global kernel-row
        int lr = kr - lbase;                    // local row 27w'+k
        if ((unsigned)lr < 108u)
          klh[lr * KL_STRIDE + col] = (_Float16)acc[r];
      }
    }
  }
  __syncthreads();  // kl produced cross-wave

  // ---- Phase 3: gather-reduce from GROUP-MAJOR fp16 xTg (R27) ----
  {
    const _Float16* xTg = (const _Float16*)xT + ((size_t)(b * 8 + g) << 18);
    const __half* klr = kl + (w * KK) * KL_STRIDE + si;
    float oacc[8];
#pragma unroll
    for (int i = 0; i < 8; ++i) oacc[i] = 0.f;

#pragma unroll 3
    for (int k = 0; k < KK; ++k) {
      unsigned off = offs[(k << 6) + si];
      float kvr = __half2float(klr[k * KL_STRIDE]);
      float kv  = (off != 0xFFFFu) ? kvr : 0.f;
      unsigned o2 = (off != 0xFFFFu) ? off : 0u;
      h8 hv = *(const h8*)(xTg + ((size_t)o2 << 3));
      oacc[0] = fmaf(kv, (float)hv[0], oacc[0]);
      oacc[1] = fmaf(kv, (float)hv[1], oacc[1]);
      oacc[2] = fmaf(kv, (float)hv[2], oacc[2]);
      oacc[3] = fmaf(kv, (float)hv[3], oacc[3]);
      oacc[4] = fmaf(kv, (float)hv[4], oacc[4]);
      oacc[5] = fmaf(kv, (float)hv[5], oacc[5]);
      oacc[6] = fmaf(kv, (float)hv[6], oacc[6]);
      oacc[7] = fmaf(kv, (float)hv[7], oacc[7]);
    }

    float* ob = out + (((size_t)b * CC + c0) << 15) + s0 + si;
#pragma unroll
    for (int i = 0; i < 8; ++i) ob[(size_t)i << 15] = oacc[i];
  }
}

// ---------------------------------------------------------------------------
// Fallback (ws too small): exact R4 fused kernel — known-good 144 us.
// ---------------------------------------------------------------------------
__global__ __launch_bounds__(256, 8) void invol_fused(
    const float* __restrict__ x, const float* __restrict__ wr,
    const float* __restrict__ wsp, const float* __restrict__ gamma,
    const float* __restrict__ beta, const float* __restrict__ mean,
    const float* __restrict__ var, float* __restrict__ out) {
  __shared__ float sv[CC * 64];
  __shared__ int offs[KK * 64];

  const int tid = threadIdx.x;
  const int blk = blockIdx.x;
  const int b   = blk >> 10;
  const int p   = (blk >> 9) & 1;
  const int s0  = (blk & 511) << 6;
  const int si  = tid & 63;
  const int w   = __builtin_amdgcn_readfirstlane(tid >> 6);
  const int g   = (p << 2) + w;

  const float* xb  = x + ((size_t)b << 21);
  const float* xs0 = xb + s0 + si;

  for (int i = tid; i < KK * 64; i += 256) {
    int k  = i >> 6;
    int f  = (k << 15) + s0 + (i & 63);
    int kw = f % 3; int u = f / 3;
    int kh = u % 3; u /= 3;
    int kd = u % 3; u /= 3;
    int ww = (u & 31) + kw - 1; u >>= 5;
    int hh = (u & 31) + kh - 1; u >>= 5;
    int dd = u + kd - 1;
    int off = -1;
    if (((unsigned)ww < 32u) & ((unsigned)hh < 32u) & ((unsigned)dd < 32u))
      off = (dd << 10) + (hh << 5) + ww;
    offs[i] = off;
  }

  {
    float acc[16];
#pragma unroll
    for (int j = 0; j < 16; ++j) acc[j] = 0.f;
#pragma unroll
    for (int half = 0; half < 2; ++half) {
      float xv[32];
#pragma unroll
      for (int c = 0; c < 32; ++c)
        xv[c] = xs0[(size_t)(half * 32 + c) << 15];
      const float* wrw = wr + (w * 16) * CC + half * 32;
#pragma unroll
      for (int j = 0; j < 16; ++j) {
        const float* r0 = wrw + j * CC;
        float a0 = 0.f, a1 = 0.f;
#pragma unroll
        for (int c = 0; c < 32; c += 2) {
          a0 = fmaf(r0[c],     xv[c],     a0);
          a1 = fmaf(r0[c + 1], xv[c + 1], a1);
        }
        acc[j] += a0 + a1;
      }
    }
#pragma unroll
    for (int j = 0; j < 16; ++j) {
      int o = w * 16 + j;
      float v = (acc[j] - mean[o]) * rsqrtf(var[o] + BN_EPS) * gamma[o] + beta[o];
      sv[o * 64 + si] = v > 0.f ? v : 0.f;
    }
  }
  __syncthreads();

  float kreg[27];
#pragma unroll
  for (int j = 0; j < KK; ++j) kreg[j] = 0.f;
#pragma unroll
  for (int e = 0; e < 8; ++e) {
    float xv[8];
#pragma unroll
    for (int c = 0; c < 8; ++c) xv[c] = sv[(e * 8 + c) * 64 + si];
    const float* wsw = wsp + (g * KK) * CC + e * 8;
#pragma unroll
    for (int j = 0; j < KK; ++j) {
      const float* r = wsw + j * CC;
      float a0 = 0.f, a1 = 0.f;
#pragma unroll
      for (int c = 0; c < 8; c += 2) {
        a0 = fmaf(r[c],     xv[c],     a0);
        a1 = fmaf(r[c + 1], xv[c + 1], a1);
      }
      kreg[j] += a0 + a1;
    }
  }

  {
    const int c0 = g << 3;
    const float* xc0 = xb + ((size_t)c0 << 15);
    float oacc[8];
#pragma unroll
    for (int i = 0; i < 8; ++i) oacc[i] = 0.f;
#pragma unroll
    for (int k = 0; k < KK; ++k) {
      int off = offs[(k << 6) + si];
      float kv = kreg[k];
      if (off >= 0) {
#pragma unroll
        for (int c8 = 0; c8 < 8; ++c8)
          oacc[c8] = fmaf(kv, xc0[off + (c8 << 15)], oacc[c8]);
      }
    }
    float* ob = out + (((size_t)b * CC + c0) << 15) + s0 + si;
#pragma unroll
    for (int i = 0; i < 8; ++i) ob[(size_t)i << 15] = oacc[i];
  }
}

extern "C" void kernel_launch(void* const* d_in, const int* in_sizes, int n_in,
                              void* d_out, int out_size, void* d_ws, size_t ws_size,
                              hipStream_t stream) {
  const float* x     = (const float*)d_in[0];
  const float* wr    = (const float*)d_in[1];
  const float* wsp   = (const float*)d_in[2];
  const float* gamma = (const float*)d_in[3];
  const float* beta  = (const float*)d_in[4];
  const float* mean  = (const float*)d_in[5];
  const float* var   = (const float*)d_in[6];
  float* out = (float*)d_out;

  const size_t need = XT_HALVES * sizeof(__half);  // 8.4 MB
  if (ws_size >= need) {
    __half* xT = (__half*)d_ws;
    xpose_kernel<<<BB * (S_TOT / 64), 256, 0, stream>>>(x, xT);
    invol_fused_xt<<<BB * 2 * (S_TOT / 64), 256, 0, stream>>>(
        x, xT, wr, wsp, gamma, beta, mean, var, out);
  } else {
    invol_fused<<<BB * 2 * (S_TOT / 64), 256, 0, stream>>>(
        x, wr, wsp, gamma, beta, mean, var, out);
  }
}